// Round 9
// baseline (31.872 us; speedup 1.0000x reference)
//
#include <hip/hip_runtime.h>

// Problem constants (fixed by reference): pred/target (8,3,224,224) fp32.
#define BINS   30
#define NB     240               // 8 batches * 30 bins
#define ROW_N  150528            // 3*224*224 elements per batch row
#define ROW_N4 37632             // float4 per row
#define NROWS  16                // 2 inputs * 8 batches
#define LGCPR  6                 // 64 chunks per row -> 1024 blocks (4/CU)
#define CPR    (1 << LGCPR)
#define G      (NROWS << LGCPR)
#define LGF    10
#define FBINS  (1 << LGF)        // 1024 fine bins
#define FW     (FBINS + 2)       // + edge bins

// exp(-0.5*((x-c)/delta)^2) = exp2(KXF*(x-c)^2), KXF = -0.5*log2(e)*900
#define KXF (-649.2627684000335f)
#define RAD (6.5f / 30.0f)       // truncate kernel at |u| > 6.5 (tail < 7e-10)
#define MAGIC 0x5A17CAFEu

// d_ws layout (u32): ghist[480] | ready | counter
// One dispatch. Block 0 zeroes ghist+counter, fences, sets ready=MAGIC.
// Every block: LDS fine hist (fixed-point interp, native ds_add_u32) ->
// local Gaussian conv to 30 u32 partials -> (after ready==MAGIC) 30
// fire-and-forget global u32 atomicAdds -> ticket++. Last ticket holder
// reduces the 480-word ghist (2 atomic loads/thread), writes the score,
// clears ready so the next replay re-initializes. u32 accumulation is
// order-independent -> bit-deterministic across replays.
__global__ __launch_bounds__(256) void hsim_onepass(
    const float* __restrict__ pred,
    const float* __restrict__ target,
    unsigned int* __restrict__ ghist,     // [2*NB]
    unsigned int* __restrict__ ready,
    unsigned int* __restrict__ counter,
    float* __restrict__ out)
{
    const int row   = blockIdx.x >> LGCPR;
    const int chunk = blockIdx.x & (CPR - 1);
    const int input_sel = row >> 3;        // 0 = pred, 1 = target
    const int batch     = row & 7;
    const int t = threadIdx.x;

    __shared__ unsigned int lh[FW];
    __shared__ float sws[4];
    __shared__ int   s_is_closer;

    // ---- block 0: initialize accumulators, then release everyone --------
    if (blockIdx.x == 0) {
        for (int i = t; i < 2 * NB; i += 256) ghist[i] = 0u;
        if (t == 0) *counter = 0u;
        __syncthreads();
        if (t == 0) {
            __threadfence();
            atomicExch(ready, MAGIC);
        }
    }

    const float4* src4 =
        (const float4*)((input_sel ? target : pred) + (size_t)batch * ROW_N);

    for (int i = t; i < FW; i += 256) lh[i] = 0u;
    __syncthreads();

    // ---- A: linear-interpolated fine histogram (native LDS u32 atomics) -
    const float Ff = (float)FBINS;
#pragma unroll 2
    for (int i = (chunk << 8) + t; i < ROW_N4; i += (CPR << 8)) {
        float4 v = src4[i];
        float xs[4] = { v.x, v.y, v.z, v.w };
#pragma unroll
        for (int k = 0; k < 4; ++k) {
            const float q  = fmaf(xs[k], Ff, -0.5f);
            const float fi = floorf(q);
            const unsigned int w1 = (unsigned int)((q - fi) * 16384.0f + 0.5f);
            const int i0 = (int)fi + 1;          // in [0, FBINS]
            atomicAdd(&lh[i0],     16384u - w1); // ds_add_u32
            atomicAdd(&lh[i0 + 1], w1);
        }
    }
    __syncthreads();

    // ---- wait for init (normally long done by now) ----------------------
    if (t == 0)
        while (atomicAdd(ready, 0u) != MAGIC)
            __builtin_amdgcn_s_sleep(2);
    __syncthreads();

    // ---- B: local windowed Gaussian conv -> 30 u32 partials -> global ---
    const int bin = t >> 3;                 // 0..31 (30 used)
    const int sub = t & 7;
    if (bin < BINS) {
        const float c = (bin + 0.5f) * (1.0f / 30.0f);
        int ilo = (int)ceilf((c - RAD) * Ff + 0.5f);
        int ihi = (int)floorf((c + RAD) * Ff + 0.5f);
        ilo = max(ilo, 0);
        ihi = min(ihi, FBINS + 1);
        const float invF = 1.0f / Ff;

        float conv = 0.0f;
        for (int f = ilo + sub; f <= ihi; f += 8) {
            const float x = ((float)f - 0.5f) * invF;   // fine-bin center
            const float d = x - c;
            conv = fmaf(__builtin_amdgcn_exp2f(KXF * d * d), (float)lh[f], conv);
        }
        conv += __shfl_xor(conv, 1, 64);
        conv += __shfl_xor(conv, 2, 64);
        conv += __shfl_xor(conv, 4, 64);
        if (sub == 0)   // fire-and-forget native u32 atomic (no return)
            atomicAdd(&ghist[row * BINS + bin], (unsigned int)(conv + 0.5f));
    }
    __syncthreads();

    // ---- ticket: last block becomes the closer --------------------------
    if (t == 0) {
        __threadfence();
        s_is_closer = (atomicAdd(counter, 1u) == G - 1u);
    }
    __syncthreads();
    if (!s_is_closer) return;
    __threadfence();

    // ---- closer: 480 coherent loads total, score, write, cleanup --------
    float term = 0.0f;
    if (t < NB) {
        const float p  = (float)atomicAdd(&ghist[t], 0u);        // pred rows
        const float tg = (float)atomicAdd(&ghist[NB + t], 0u);   // target rows
        term = (p == 0.0f) ? 0.0f : fminf(p, tg) / p;
    }
#pragma unroll
    for (int off = 32; off >= 1; off >>= 1)
        term += __shfl_xor(term, off, 64);
    if ((t & 63) == 0) sws[t >> 6] = term;
    __syncthreads();
    if (t == 0) {
        out[0] = (sws[0] + sws[1] + sws[2] + sws[3]) * (1.0f / (float)NB);
        __threadfence();
        atomicExch(ready, 0u);   // next replay re-initializes
    }
}

extern "C" void kernel_launch(void* const* d_in, const int* in_sizes, int n_in,
                              void* d_out, int out_size, void* d_ws, size_t ws_size,
                              hipStream_t stream) {
    const float* pred   = (const float*)d_in[0];
    const float* target = (const float*)d_in[1];

    unsigned int* ghist   = (unsigned int*)d_ws;   // 480 u32
    unsigned int* ready   = ghist + 2 * NB;
    unsigned int* counter = ready + 1;

    hsim_onepass<<<G, 256, 0, stream>>>(pred, target, ghist, ready, counter,
                                        (float*)d_out);
}

// Round 10
// 24.267 us; speedup vs baseline: 1.3134x; 1.3134x over previous
//
#include <hip/hip_runtime.h>

// Problem constants (fixed by reference): pred/target (8,3,224,224) fp32.
#define BINS   30
#define NB     240               // 8 batches * 30 bins
#define ROW_N  150528            // 3*224*224 elements per batch row
#define ROW_N4 37632             // float4 per row
#define NROWS  16                // 2 inputs * 8 batches
#define LGCPR  5                 // 32 chunks per row -> 512 blocks (2/CU)
#define CPR    (1 << LGCPR)
#define G      (NROWS << LGCPR)
#define LGF    11
#define FBINS  (1 << LGF)        // 2048 fine bins
#define FW     (FBINS + 2)       // + edge bins

// exp(-0.5*((x-c)/delta)^2) = exp2(KXF*(x-c)^2), KXF = -0.5*log2(e)*900
#define KXF (-649.2627684000335f)
#define RAD (6.5f / 30.0f)       // truncate kernel at |u| > 6.5 (tail < 7e-10)
#define MAGIC 0x5A17CAFEu

__device__ __forceinline__ void bin4(unsigned int* lh, float4 v) {
    const float Ff = (float)FBINS;
    float xs[4] = { v.x, v.y, v.z, v.w };
#pragma unroll
    for (int k = 0; k < 4; ++k) {
        const float q  = fmaf(xs[k], Ff, -0.5f);
        const float fi = floorf(q);
        const unsigned int w1 = (unsigned int)((q - fi) * 16384.0f + 0.5f);
        const int i0 = (int)fi + 1;          // in [0, FBINS]
        atomicAdd(&lh[i0],     16384u - w1); // ds_add_u32 (no return)
        atomicAdd(&lh[i0 + 1], w1);
    }
}

// d_ws layout (u32): ghist[480] | ready | counter
// Single dispatch; R8 structure (proven 24.9us, absmax 0.0) with ONE change:
// phase A issues all 4-5 of a thread's float4 loads back-to-back before
// processing, so HBM latency (~900cy) is paid once, not ~5 times, at 2
// blocks/CU occupancy.
__global__ __launch_bounds__(256) void hsim_onepass(
    const float* __restrict__ pred,
    const float* __restrict__ target,
    unsigned int* __restrict__ ghist,     // [2*NB]
    unsigned int* __restrict__ ready,
    unsigned int* __restrict__ counter,
    float* __restrict__ out)
{
    const int row   = blockIdx.x >> LGCPR;
    const int chunk = blockIdx.x & (CPR - 1);
    const int input_sel = row >> 3;        // 0 = pred, 1 = target
    const int batch     = row & 7;
    const int t = threadIdx.x;

    __shared__ unsigned int lh[FW];
    __shared__ float sws[4];
    __shared__ int   s_is_closer;

    // ---- block 0: initialize accumulators, then release everyone --------
    if (blockIdx.x == 0) {
        for (int i = t; i < 2 * NB; i += 256) ghist[i] = 0u;
        if (t == 0) *counter = 0u;
        __syncthreads();
        if (t == 0) {
            __threadfence();
            atomicExch(ready, MAGIC);
        }
    }

    const float4* src4 =
        (const float4*)((input_sel ? target : pred) + (size_t)batch * ROW_N);

    // ---- A: issue ALL this thread's loads first (latency overlap) -------
    const int base = (chunk << 8) + t;     // [0, 8192)
    const float4 a = src4[base];
    const float4 b = src4[base + 1 * CPR * 256];
    const float4 c = src4[base + 2 * CPR * 256];
    const float4 d = src4[base + 3 * CPR * 256];   // max 32767 < 37632: safe
    const bool  has5 = (chunk < 19);       // block-uniform: 4*8192+base < 37632
    float4 e;
    if (has5) e = src4[base + 4 * CPR * 256];

    for (int i = t; i < FW; i += 256) lh[i] = 0u;
    __syncthreads();

    bin4(lh, a);
    bin4(lh, b);
    bin4(lh, c);
    bin4(lh, d);
    if (has5) bin4(lh, e);
    __syncthreads();

    // ---- wait for init (normally long done by now) ----------------------
    if (t == 0)
        while (atomicAdd(ready, 0u) != MAGIC)
            __builtin_amdgcn_s_sleep(2);
    __syncthreads();

    // ---- B: local windowed Gaussian conv -> 30 u32 partials -> global ---
    const int bin = t >> 3;                 // 0..31 (30 used)
    const int sub = t & 7;
    const float Ff = (float)FBINS;
    if (bin < BINS) {
        const float c0 = (bin + 0.5f) * (1.0f / 30.0f);
        int ilo = (int)ceilf((c0 - RAD) * Ff + 0.5f);
        int ihi = (int)floorf((c0 + RAD) * Ff + 0.5f);
        ilo = max(ilo, 0);
        ihi = min(ihi, FBINS + 1);
        const float invF = 1.0f / Ff;

        float conv = 0.0f;
        for (int f = ilo + sub; f <= ihi; f += 8) {
            const float x = ((float)f - 0.5f) * invF;   // fine-bin center
            const float dd = x - c0;
            conv = fmaf(__builtin_amdgcn_exp2f(KXF * dd * dd), (float)lh[f], conv);
        }
        conv += __shfl_xor(conv, 1, 64);
        conv += __shfl_xor(conv, 2, 64);
        conv += __shfl_xor(conv, 4, 64);
        if (sub == 0)   // fire-and-forget native u32 atomic (no return)
            atomicAdd(&ghist[row * BINS + bin], (unsigned int)(conv + 0.5f));
    }
    __syncthreads();

    // ---- ticket: last block becomes the closer --------------------------
    if (t == 0) {
        __threadfence();
        s_is_closer = (atomicAdd(counter, 1u) == G - 1u);
    }
    __syncthreads();
    if (!s_is_closer) return;
    __threadfence();

    // ---- closer: 480 coherent loads total, score, write, cleanup --------
    float term = 0.0f;
    if (t < NB) {
        const float p  = (float)atomicAdd(&ghist[t], 0u);        // pred rows
        const float tg = (float)atomicAdd(&ghist[NB + t], 0u);   // target rows
        term = (p == 0.0f) ? 0.0f : fminf(p, tg) / p;
    }
#pragma unroll
    for (int off = 32; off >= 1; off >>= 1)
        term += __shfl_xor(term, off, 64);
    if ((t & 63) == 0) sws[t >> 6] = term;
    __syncthreads();
    if (t == 0) {
        out[0] = (sws[0] + sws[1] + sws[2] + sws[3]) * (1.0f / (float)NB);
        __threadfence();
        atomicExch(ready, 0u);   // next replay re-initializes
    }
}

extern "C" void kernel_launch(void* const* d_in, const int* in_sizes, int n_in,
                              void* d_out, int out_size, void* d_ws, size_t ws_size,
                              hipStream_t stream) {
    const float* pred   = (const float*)d_in[0];
    const float* target = (const float*)d_in[1];

    unsigned int* ghist   = (unsigned int*)d_ws;   // 480 u32
    unsigned int* ready   = ghist + 2 * NB;
    unsigned int* counter = ready + 1;

    hsim_onepass<<<G, 256, 0, stream>>>(pred, target, ghist, ready, counter,
                                        (float*)d_out);
}

// Round 11
// 20.380 us; speedup vs baseline: 1.5639x; 1.1907x over previous
//
#include <hip/hip_runtime.h>

// Problem constants (fixed by reference): pred/target (8,3,224,224) fp32.
#define BINS   30
#define NB     240               // 8 batches * 30 bins
#define ROW_N  150528            // 3*224*224 elements per batch row
#define ROW_N4 37632             // float4 per row
#define NROWS  16                // 2 inputs * 8 batches
#define LGCPR  5                 // 32 chunks per row -> 512 blocks (2/CU)
#define CPR    (1 << LGCPR)
#define G      (NROWS << LGCPR)
#define LGF    11
#define FBINS  (1 << LGF)        // 2048 fine bins
#define FW     (FBINS + 2)       // + edge bins
#define NCELL  8                 // ticket cells (G/NCELL = 64 per cell)

// exp(-0.5*((x-c)/delta)^2) = exp2(KXF*(x-c)^2), KXF = -0.5*log2(e)*900
#define KXF (-649.2627684000335f)
#define RAD (6.5f / 30.0f)       // truncate kernel at |u| > 6.5 (tail < 7e-10)
#define MAGIC 0x5A17CAFEu

__device__ __forceinline__ void bin4(unsigned int* lh, float4 v) {
    const float Ff = (float)FBINS;
    float xs[4] = { v.x, v.y, v.z, v.w };
#pragma unroll
    for (int k = 0; k < 4; ++k) {
        const float q  = fmaf(xs[k], Ff, -0.5f);
        const float fi = floorf(q);
        const unsigned int w1 = (unsigned int)((q - fi) * 16384.0f + 0.5f);
        const int i0 = (int)fi + 1;          // in [0, FBINS]
        atomicAdd(&lh[i0],     16384u - w1); // ds_add_u32 (no return)
        atomicAdd(&lh[i0 + 1], w1);
    }
}

// d_ws layout (u32): ghist[480] | ready | cells[8] | lvl2
// Single dispatch. Synchronization model (no __threadfence anywhere):
//  - __syncthreads() drains vmcnt(0) per wave (HIP barrier semantics), so
//    after the post-phase-B barrier every block's ghist atomics are complete
//    at the coherent point BEFORE its ticket increment (release ordering).
//  - closer reads ghist via atomic-returns (coherent-point reads: acquire).
//  - ghist zeroing uses atomicExch (coherent regardless of XCD L2 state).
//  - two-level ticket: 8 cells x 64 increments (parallel), last-in-cell
//    bumps lvl2; closer = last lvl2. Removes 512-to-1-address serialization.
__global__ __launch_bounds__(256) void hsim_onepass(
    const float* __restrict__ pred,
    const float* __restrict__ target,
    unsigned int* __restrict__ ghist,     // [2*NB]
    unsigned int* __restrict__ ready,
    unsigned int* __restrict__ cells,     // [NCELL + 1]
    float* __restrict__ out)
{
    const int row   = blockIdx.x >> LGCPR;
    const int chunk = blockIdx.x & (CPR - 1);
    const int input_sel = row >> 3;        // 0 = pred, 1 = target
    const int batch     = row & 7;
    const int t = threadIdx.x;

    __shared__ unsigned int lh[FW];
    __shared__ float sws[4];
    __shared__ int   s_is_closer;

    // ---- block 0: initialize accumulators, then release everyone --------
    if (blockIdx.x == 0) {
        for (int i = t; i < 2 * NB; i += 256) atomicExch(&ghist[i], 0u);
        if (t < NCELL + 1) atomicExch(&cells[t], 0u);
        __syncthreads();                    // drains the exchanges (vmcnt)
        if (t == 0) atomicExch(ready, MAGIC);
    }

    const float4* src4 =
        (const float4*)((input_sel ? target : pred) + (size_t)batch * ROW_N);

    // ---- A: issue ALL this thread's loads first (latency overlap) -------
    const int base = (chunk << 8) + t;     // [0, 8192)
    const float4 a = src4[base];
    const float4 b = src4[base + 1 * CPR * 256];
    const float4 c = src4[base + 2 * CPR * 256];
    const float4 d = src4[base + 3 * CPR * 256];   // max 32767 < 37632: safe
    const bool  has5 = (chunk < 19);       // block-uniform
    float4 e;
    if (has5) e = src4[base + 4 * CPR * 256];

    for (int i = t; i < FW; i += 256) lh[i] = 0u;
    __syncthreads();

    bin4(lh, a);
    bin4(lh, b);
    bin4(lh, c);
    bin4(lh, d);
    if (has5) bin4(lh, e);
    __syncthreads();

    // ---- wait for init (normally long done by now) ----------------------
    if (t == 0)
        while (atomicAdd(ready, 0u) != MAGIC)
            __builtin_amdgcn_s_sleep(2);
    __syncthreads();

    // ---- B: local windowed Gaussian conv -> 30 u32 partials -> global ---
    const int bin = t >> 3;                 // 0..31 (30 used)
    const int sub = t & 7;
    const float Ff = (float)FBINS;
    if (bin < BINS) {
        const float c0 = (bin + 0.5f) * (1.0f / 30.0f);
        int ilo = (int)ceilf((c0 - RAD) * Ff + 0.5f);
        int ihi = (int)floorf((c0 + RAD) * Ff + 0.5f);
        ilo = max(ilo, 0);
        ihi = min(ihi, FBINS + 1);
        const float invF = 1.0f / Ff;

        float conv = 0.0f;
        for (int f = ilo + sub; f <= ihi; f += 8) {
            const float x = ((float)f - 0.5f) * invF;   // fine-bin center
            const float dd = x - c0;
            conv = fmaf(__builtin_amdgcn_exp2f(KXF * dd * dd), (float)lh[f], conv);
        }
        conv += __shfl_xor(conv, 1, 64);
        conv += __shfl_xor(conv, 2, 64);
        conv += __shfl_xor(conv, 4, 64);
        if (sub == 0)   // fire-and-forget native u32 atomic (no return)
            atomicAdd(&ghist[row * BINS + bin], (unsigned int)(conv + 0.5f));
    }
    __syncthreads();    // barrier drains vmcnt -> ghist adds complete (release)

    // ---- two-level ticket: last block overall becomes the closer --------
    if (t == 0) {
        const unsigned int cell = blockIdx.x & (NCELL - 1);
        const unsigned int r    = atomicAdd(&cells[cell], 1u);
        int closer = 0;
        if (r == (G / NCELL) - 1u)                      // last in my cell
            closer = (atomicAdd(&cells[NCELL], 1u) == NCELL - 1u);
        s_is_closer = closer;
    }
    __syncthreads();
    if (!s_is_closer) return;

    // ---- closer: 480 coherent loads total, score, write, cleanup --------
    float term = 0.0f;
    if (t < NB) {
        const float p  = (float)atomicAdd(&ghist[t], 0u);        // pred rows
        const float tg = (float)atomicAdd(&ghist[NB + t], 0u);   // target rows
        term = (p == 0.0f) ? 0.0f : fminf(p, tg) / p;
    }
#pragma unroll
    for (int off = 32; off >= 1; off >>= 1)
        term += __shfl_xor(term, off, 64);
    if ((t & 63) == 0) sws[t >> 6] = term;
    __syncthreads();
    if (t == 0) {
        out[0] = (sws[0] + sws[1] + sws[2] + sws[3]) * (1.0f / (float)NB);
        atomicExch(ready, 0u);   // next replay re-initializes
    }
}

extern "C" void kernel_launch(void* const* d_in, const int* in_sizes, int n_in,
                              void* d_out, int out_size, void* d_ws, size_t ws_size,
                              hipStream_t stream) {
    const float* pred   = (const float*)d_in[0];
    const float* target = (const float*)d_in[1];

    unsigned int* ghist = (unsigned int*)d_ws;   // 480 u32
    unsigned int* ready = ghist + 2 * NB;
    unsigned int* cells = ready + 1;             // 9 u32

    hsim_onepass<<<G, 256, 0, stream>>>(pred, target, ghist, ready, cells,
                                        (float*)d_out);
}

// Round 12
// 17.999 us; speedup vs baseline: 1.7707x; 1.1323x over previous
//
#include <hip/hip_runtime.h>

// Problem constants (fixed by reference): pred/target (8,3,224,224) fp32.
#define BINS   30
#define NB     240               // 8 batches * 30 bins
#define ROW_N  150528            // 3*224*224 elements per batch row
#define ROW_N4 37632             // float4 per row
#define NROWS  16                // 2 inputs * 8 batches
#define LGCPR  5                 // 32 chunks per row -> 512 blocks
#define CPR    (1 << LGCPR)
#define G      (NROWS << LGCPR)
#define NT     512               // threads per block (8 waves, 4 waves/SIMD)
#define LGF    11
#define FBINS  (1 << LGF)        // 2048 fine bins
#define FW     (FBINS + 2)       // + edge bins
#define NCELL  8                 // ticket cells (G/NCELL = 64 per cell)

// exp(-0.5*((x-c)/delta)^2) = exp2(KXF*(x-c)^2), KXF = -0.5*log2(e)*900
#define KXF (-649.2627684000335f)
#define RAD (6.5f / 30.0f)       // truncate kernel at |u| > 6.5 (tail < 7e-10)
#define MAGIC 0x5A17CAFEu

__device__ __forceinline__ void bin4(unsigned int* lh, float4 v) {
    const float Ff = (float)FBINS;
    float xs[4] = { v.x, v.y, v.z, v.w };
#pragma unroll
    for (int k = 0; k < 4; ++k) {
        const float q  = fmaf(xs[k], Ff, -0.5f);
        const float fi = floorf(q);
        const unsigned int w1 = (unsigned int)((q - fi) * 16384.0f + 0.5f);
        const int i0 = (int)fi + 1;          // in [0, FBINS]
        atomicAdd(&lh[i0],     16384u - w1); // ds_add_u32 (no return)
        atomicAdd(&lh[i0 + 1], w1);
    }
}

// d_ws layout (u32): ghist[480] | ready | cells[8] | lvl2
// Single dispatch, R11 sync structure (proven 20.4us, absmax 0.0), ONE
// change: 512-thread blocks (same 512-block grid) -> 4 waves/SIMD for the
// latency-limited streaming phase; ghist contention & ticket depth unchanged.
__global__ __launch_bounds__(NT) void hsim_onepass(
    const float* __restrict__ pred,
    const float* __restrict__ target,
    unsigned int* __restrict__ ghist,     // [2*NB]
    unsigned int* __restrict__ ready,
    unsigned int* __restrict__ cells,     // [NCELL + 1]
    float* __restrict__ out)
{
    const int row   = blockIdx.x >> LGCPR;
    const int chunk = blockIdx.x & (CPR - 1);
    const int input_sel = row >> 3;        // 0 = pred, 1 = target
    const int batch     = row & 7;
    const int t = threadIdx.x;

    __shared__ unsigned int lh[FW];
    __shared__ float sws[NT / 64];
    __shared__ int   s_is_closer;

    // ---- block 0: initialize accumulators, then release everyone --------
    if (blockIdx.x == 0) {
        if (t < 2 * NB) atomicExch(&ghist[t], 0u);
        if (t >= 2 * NB && t < 2 * NB + NCELL + 1) atomicExch(&cells[t - 2 * NB], 0u);
        __syncthreads();                    // drains the exchanges (vmcnt)
        if (t == 0) atomicExch(ready, MAGIC);
    }

    const float4* src4 =
        (const float4*)((input_sel ? target : pred) + (size_t)batch * ROW_N);

    // ---- A: issue this thread's loads back-to-back (latency overlap) ----
    const int base = (chunk << 9) + t;     // [0, 16384)
    const float4 a = src4[base];
    const float4 b = src4[base + CPR * NT];          // max 32767 < 37632: safe
    const int  i3  = base + 2 * CPR * NT;
    const bool has3 = (i3 < ROW_N4);
    float4 c;
    if (has3) c = src4[i3];

    for (int i = t; i < FW; i += NT) lh[i] = 0u;
    __syncthreads();

    bin4(lh, a);
    bin4(lh, b);
    if (has3) bin4(lh, c);
    __syncthreads();

    // ---- wait for init (normally long done by now) ----------------------
    if (t == 0)
        while (atomicAdd(ready, 0u) != MAGIC)
            __builtin_amdgcn_s_sleep(2);
    __syncthreads();

    // ---- B: local windowed Gaussian conv -> 30 u32 partials -> global ---
    const int bin = t >> 4;                 // 0..31 (30 used)
    const int sub = t & 15;
    const float Ff = (float)FBINS;
    if (bin < BINS) {
        const float c0 = (bin + 0.5f) * (1.0f / 30.0f);
        int ilo = (int)ceilf((c0 - RAD) * Ff + 0.5f);
        int ihi = (int)floorf((c0 + RAD) * Ff + 0.5f);
        ilo = max(ilo, 0);
        ihi = min(ihi, FBINS + 1);
        const float invF = 1.0f / Ff;

        float conv = 0.0f;
        for (int f = ilo + sub; f <= ihi; f += 16) {
            const float x = ((float)f - 0.5f) * invF;   // fine-bin center
            const float dd = x - c0;
            conv = fmaf(__builtin_amdgcn_exp2f(KXF * dd * dd), (float)lh[f], conv);
        }
        conv += __shfl_xor(conv, 1, 64);
        conv += __shfl_xor(conv, 2, 64);
        conv += __shfl_xor(conv, 4, 64);
        conv += __shfl_xor(conv, 8, 64);
        if (sub == 0)   // fire-and-forget native u32 atomic (no return)
            atomicAdd(&ghist[row * BINS + bin], (unsigned int)(conv + 0.5f));
    }
    __syncthreads();    // barrier drains vmcnt -> ghist adds complete (release)

    // ---- two-level ticket: last block overall becomes the closer --------
    if (t == 0) {
        const unsigned int cell = blockIdx.x & (NCELL - 1);
        const unsigned int r    = atomicAdd(&cells[cell], 1u);
        int closer = 0;
        if (r == (G / NCELL) - 1u)                      // last in my cell
            closer = (atomicAdd(&cells[NCELL], 1u) == NCELL - 1u);
        s_is_closer = closer;
    }
    __syncthreads();
    if (!s_is_closer) return;

    // ---- closer: 480 coherent loads total, score, write, cleanup --------
    float term = 0.0f;
    if (t < NB) {
        const float p  = (float)atomicAdd(&ghist[t], 0u);        // pred rows
        const float tg = (float)atomicAdd(&ghist[NB + t], 0u);   // target rows
        term = (p == 0.0f) ? 0.0f : fminf(p, tg) / p;
    }
#pragma unroll
    for (int off = 32; off >= 1; off >>= 1)
        term += __shfl_xor(term, off, 64);
    if ((t & 63) == 0) sws[t >> 6] = term;
    __syncthreads();
    if (t == 0) {
        float s = 0.0f;
#pragma unroll
        for (int w = 0; w < NT / 64; ++w) s += sws[w];
        out[0] = s * (1.0f / (float)NB);
        atomicExch(ready, 0u);   // next replay re-initializes
    }
}

extern "C" void kernel_launch(void* const* d_in, const int* in_sizes, int n_in,
                              void* d_out, int out_size, void* d_ws, size_t ws_size,
                              hipStream_t stream) {
    const float* pred   = (const float*)d_in[0];
    const float* target = (const float*)d_in[1];

    unsigned int* ghist = (unsigned int*)d_ws;   // 480 u32
    unsigned int* ready = ghist + 2 * NB;
    unsigned int* cells = ready + 1;             // 9 u32

    hsim_onepass<<<G, NT, 0, stream>>>(pred, target, ghist, ready, cells,
                                       (float*)d_out);
}

// Round 13
// 17.632 us; speedup vs baseline: 1.8076x; 1.0208x over previous
//
#include <hip/hip_runtime.h>

// Problem constants (fixed by reference): pred/target (8,3,224,224) fp32.
#define BINS   30
#define NB     240               // 8 batches * 30 bins
#define ROW_N  150528            // 3*224*224 elements per batch row
#define ROW_N4 37632             // float4 per row
#define NROWS  16                // 2 inputs * 8 batches
#define LGCPR  5                 // 32 chunks per row -> 512 blocks
#define CPR    (1 << LGCPR)
#define G      (NROWS << LGCPR)
#define NT     512               // threads per block (8 waves, 4 waves/SIMD)
#define LGF    11
#define FBINS  (1 << LGF)        // 2048 fine bins
#define FW     (FBINS + 2)       // + edge bins
#define NCELL  8                 // ticket cells (G/NCELL = 64 per cell)
#define CSCALE 4096.0f           // conv->u32 fixed-point (150528*4096 < 2^32)

// exp(-0.5*((x-c)/delta)^2) = exp2(KXF*(x-c)^2), KXF = -0.5*log2(e)*900
#define KXF (-649.2627684000335f)
#define RAD (6.5f / 30.0f)       // truncate kernel at |u| > 6.5 (tail < 7e-10)
#define MAGIC 0x5A17CAFEu

// Nearest-bin counting: idx = floor(x*F)+1 in [1, F] for x in [0,1).
// 1 VALU fma + cvt + 1 LDS atomic per element (vs 8 ops + 2 atomics interp).
// Nearest-rounding error: per-elem <= |g'|*h/2*30 ~ 4.4e-3, random sign ->
// ~1 absolute on bins ~5000 -> ~2e-4 relative score error (threshold 2e-2).
__device__ __forceinline__ void bin4(unsigned int* lh, float4 v) {
    const float Ff = (float)FBINS;
    atomicAdd(&lh[(int)fmaf(v.x, Ff, 1.0f)], 1u);   // ds_add_u32, no return
    atomicAdd(&lh[(int)fmaf(v.y, Ff, 1.0f)], 1u);
    atomicAdd(&lh[(int)fmaf(v.z, Ff, 1.0f)], 1u);
    atomicAdd(&lh[(int)fmaf(v.w, Ff, 1.0f)], 1u);
}

// d_ws layout (u32): ghist[480] | ready | cells[8] | lvl2
// Single dispatch, R11/R12 sync structure (proven, absmax 0.0):
//  - __syncthreads() drains vmcnt per wave -> release ordering for the
//    fire-and-forget ghist atomics before the ticket increment.
//  - closer reads ghist via atomic-returns (coherent acquire).
//  - two-level ticket removes single-address serialization.
__global__ __launch_bounds__(NT) void hsim_onepass(
    const float* __restrict__ pred,
    const float* __restrict__ target,
    unsigned int* __restrict__ ghist,     // [2*NB]
    unsigned int* __restrict__ ready,
    unsigned int* __restrict__ cells,     // [NCELL + 1]
    float* __restrict__ out)
{
    const int row   = blockIdx.x >> LGCPR;
    const int chunk = blockIdx.x & (CPR - 1);
    const int input_sel = row >> 3;        // 0 = pred, 1 = target
    const int batch     = row & 7;
    const int t = threadIdx.x;

    __shared__ unsigned int lh[FW];
    __shared__ float sws[NT / 64];
    __shared__ int   s_is_closer;

    // ---- block 0: initialize accumulators, then release everyone --------
    if (blockIdx.x == 0) {
        if (t < 2 * NB) atomicExch(&ghist[t], 0u);
        if (t >= 2 * NB && t < 2 * NB + NCELL + 1) atomicExch(&cells[t - 2 * NB], 0u);
        __syncthreads();                    // drains the exchanges (vmcnt)
        if (t == 0) atomicExch(ready, MAGIC);
    }

    const float4* src4 =
        (const float4*)((input_sel ? target : pred) + (size_t)batch * ROW_N);

    // ---- A: issue this thread's loads back-to-back (latency overlap) ----
    const int base = (chunk << 9) + t;     // [0, 16384)
    const float4 a = src4[base];
    const float4 b = src4[base + CPR * NT];          // max 32767 < 37632: safe
    const int  i3  = base + 2 * CPR * NT;
    const bool has3 = (i3 < ROW_N4);
    float4 c;
    if (has3) c = src4[i3];

    for (int i = t; i < FW; i += NT) lh[i] = 0u;
    __syncthreads();

    bin4(lh, a);
    bin4(lh, b);
    if (has3) bin4(lh, c);
    __syncthreads();

    // ---- wait for init (normally long done by now) ----------------------
    if (t == 0)
        while (atomicAdd(ready, 0u) != MAGIC)
            __builtin_amdgcn_s_sleep(2);
    __syncthreads();

    // ---- B: local windowed Gaussian conv -> 30 u32 partials -> global ---
    const int bin = t >> 4;                 // 0..31 (30 used)
    const int sub = t & 15;
    const float Ff = (float)FBINS;
    if (bin < BINS) {
        const float c0 = (bin + 0.5f) * (1.0f / 30.0f);
        int ilo = (int)ceilf((c0 - RAD) * Ff + 0.5f);
        int ihi = (int)floorf((c0 + RAD) * Ff + 0.5f);
        ilo = max(ilo, 0);
        ihi = min(ihi, FBINS + 1);
        const float invF = 1.0f / Ff;

        float conv = 0.0f;
        for (int f = ilo + sub; f <= ihi; f += 16) {
            const float x = ((float)f - 0.5f) * invF;   // fine-bin center
            const float dd = x - c0;
            conv = fmaf(__builtin_amdgcn_exp2f(KXF * dd * dd), (float)lh[f], conv);
        }
        conv += __shfl_xor(conv, 1, 64);
        conv += __shfl_xor(conv, 2, 64);
        conv += __shfl_xor(conv, 4, 64);
        conv += __shfl_xor(conv, 8, 64);
        if (sub == 0)   // fire-and-forget native u32 atomic (no return)
            atomicAdd(&ghist[row * BINS + bin],
                      (unsigned int)(conv * CSCALE + 0.5f));
    }
    __syncthreads();    // barrier drains vmcnt -> ghist adds complete (release)

    // ---- two-level ticket: last block overall becomes the closer --------
    if (t == 0) {
        const unsigned int cell = blockIdx.x & (NCELL - 1);
        const unsigned int r    = atomicAdd(&cells[cell], 1u);
        int closer = 0;
        if (r == (G / NCELL) - 1u)                      // last in my cell
            closer = (atomicAdd(&cells[NCELL], 1u) == NCELL - 1u);
        s_is_closer = closer;
    }
    __syncthreads();
    if (!s_is_closer) return;

    // ---- closer: 480 coherent loads total, score, write, cleanup --------
    float term = 0.0f;
    if (t < NB) {
        const float p  = (float)atomicAdd(&ghist[t], 0u);        // pred rows
        const float tg = (float)atomicAdd(&ghist[NB + t], 0u);   // target rows
        term = (p == 0.0f) ? 0.0f : fminf(p, tg) / p;
    }
#pragma unroll
    for (int off = 32; off >= 1; off >>= 1)
        term += __shfl_xor(term, off, 64);
    if ((t & 63) == 0) sws[t >> 6] = term;
    __syncthreads();
    if (t == 0) {
        float s = 0.0f;
#pragma unroll
        for (int w = 0; w < NT / 64; ++w) s += sws[w];
        out[0] = s * (1.0f / (float)NB);
        atomicExch(ready, 0u);   // next replay re-initializes
    }
}

extern "C" void kernel_launch(void* const* d_in, const int* in_sizes, int n_in,
                              void* d_out, int out_size, void* d_ws, size_t ws_size,
                              hipStream_t stream) {
    const float* pred   = (const float*)d_in[0];
    const float* target = (const float*)d_in[1];

    unsigned int* ghist = (unsigned int*)d_ws;   // 480 u32
    unsigned int* ready = ghist + 2 * NB;
    unsigned int* cells = ready + 1;             // 9 u32

    hsim_onepass<<<G, NT, 0, stream>>>(pred, target, ghist, ready, cells,
                                       (float*)d_out);
}